// Round 1
// baseline (500.316 us; speedup 1.0000x reference)
//
#include <hip/hip_runtime.h>

#define NSEQ   2000
#define CHUNK  200
#define NCHUNK (NSEQ / CHUNK)
#define GATES  40
#define HID    10

__device__ __forceinline__ float fexp(float x) {
    // e^x = 2^(x*log2(e)); v_exp_f32 computes 2^x
    return __builtin_amdgcn_exp2f(x * 1.4426950408889634f);
}
__device__ __forceinline__ float frcp(float x) {
    return __builtin_amdgcn_rcpf(x);
}

// quad_perm broadcast: every lane of a 4-lane quad gets the quad's lane CTRL/0x55
template <int CTRL>
__device__ __forceinline__ float qb(float v) {
    return __int_as_float(
        __builtin_amdgcn_update_dpp(0, __float_as_int(v), CTRL, 0xF, 0xF, false));
}

// Compute one row's gate pre-activations xg[40] = W_ih @ [mz(u); it(v)] + b_ih + b_hh
__device__ __attribute__((noinline)) void compute_row(
    int r, float* dst,
    const float* __restrict__ x,
    const float* __restrict__ Wmz1, const float* __restrict__ bmz1,
    const float* __restrict__ Wmz2, const float* __restrict__ bmz2,
    const float* __restrict__ Win1, const float* __restrict__ bin1,
    const float* __restrict__ Win2, const float* __restrict__ bin2,
    const float* __restrict__ Wih,
    const float* __restrict__ bih,  const float* __restrict__ bhh)
{
    const float u = x[2 * r];
    const float w = x[2 * r + 1];
    float tr[32];
    {
        float a[32];
#pragma unroll
        for (int i = 0; i < 32; i++) a[i] = fmaxf(fmaf(Wmz1[i], u, bmz1[i]), 0.f);
#pragma unroll
        for (int o = 0; o < 16; o++) {
            float acc = bmz2[o];
#pragma unroll
            for (int k = 0; k < 32; k++) acc = fmaf(Wmz2[o * 32 + k], a[k], acc);
            tr[o] = fmaxf(acc, 0.f);
        }
#pragma unroll
        for (int i = 0; i < 32; i++) a[i] = fmaxf(fmaf(Win1[i], w, bin1[i]), 0.f);
#pragma unroll
        for (int o = 0; o < 16; o++) {
            float acc = bin2[o];
#pragma unroll
            for (int k = 0; k < 32; k++) acc = fmaf(Win2[o * 32 + k], a[k], acc);
            tr[16 + o] = fmaxf(acc, 0.f);
        }
    }
#pragma unroll
    for (int g = 0; g < GATES; g++) {
        float acc = bih[g] + bhh[g];
#pragma unroll
        for (int k = 0; k < 32; k++) acc = fmaf(Wih[g * 32 + k], tr[k], acc);
        dst[g] = acc;
    }
}

extern "C" __global__ void __launch_bounds__(512)
msembed_kernel(const float* __restrict__ x,
               const float* __restrict__ Wmz1, const float* __restrict__ bmz1,
               const float* __restrict__ Wmz2, const float* __restrict__ bmz2,
               const float* __restrict__ Win1, const float* __restrict__ bin1,
               const float* __restrict__ Win2, const float* __restrict__ bin2,
               const float* __restrict__ Wih,  const float* __restrict__ Whh,
               const float* __restrict__ bih,  const float* __restrict__ bhh,
               float* __restrict__ out)
{
    // double-buffered xg chunks: 2 * 200 rows * 40 gates * 4B = 64,000 B
    __shared__ float s_xg[2][CHUNK * GATES];
    const int tid = threadIdx.x;

    // ---- chunk 0 precompute (all waves help) ----
    if (tid < CHUNK)
        compute_row(tid, &s_xg[0][tid * GATES], x,
                    Wmz1, bmz1, Wmz2, bmz2, Win1, bin1, Win2, bin2, Wih, bih, bhh);

    // ---- wave-0 recurrence state (quad layout: lane 4j+t = gate t of unit j) ----
    const int lane = tid & 63;
    const int tpe  = lane & 3;          // 0=i 1=f 2=g 3=o
    int j = lane >> 2;                  // hidden unit
    const bool writer = (tpe == 0) && (j < HID);
    if (j > HID - 1) j = HID - 1;       // clamp lanes 40-63 to stay in-bounds
    const int grow = tpe * 10 + j;      // pytorch gate row 0..39

    float whh[HID];
#pragma unroll
    for (int k = 0; k < HID; k++) whh[k] = Whh[grow * HID + k];

    // unified nonlinearity: s = fma(p, rcp(1 + exp(m*x)), q)
    const float m  = (tpe == 2) ?  2.f : -1.f;
    const float pp = (tpe == 2) ? -2.f :  1.f;
    const float qq = (tpe == 2) ?  1.f :  0.f;
    float h = 0.f, c = 0.f;

    for (int ch = 0; ch < NCHUNK; ch++) {
        __syncthreads();   // chunk ch's xg is now visible
        if (tid < 64) {
            // ---- recurrence over this chunk ----
            const float* buf = &s_xg[ch & 1][0];
            float xg_n = buf[grow];                       // prefetch step 0
            float* op = out + (ch * CHUNK) * HID + j;
            for (int s = 0; s < CHUNK; s++) {
                const float xv = xg_n;
                const int sn = (s + 1 < CHUNK) ? s + 1 : s;
                xg_n = buf[sn * GATES + grow];            // prefetch next step

                // broadcast h via readlane -> SGPRs
                float hs[HID];
#pragma unroll
                for (int k = 0; k < HID; k++)
                    hs[k] = __uint_as_float(
                        __builtin_amdgcn_readlane(__float_as_uint(h), 4 * k));

                // gate pre-activation: xg + W_hh . h  (2 FMA chains)
                float a0 = xv, a1 = 0.f;
#pragma unroll
                for (int k = 0; k < 5; k++) {
                    a0 = fmaf(hs[2 * k],     whh[2 * k],     a0);
                    a1 = fmaf(hs[2 * k + 1], whh[2 * k + 1], a1);
                }
                const float g = a0 + a1;

                // all 4 nonlinearities in one exp+rcp (per-lane constants)
                const float e  = fexp(m * g);
                const float rr = frcp(1.f + e);
                const float sv = fmaf(pp, rr, qq);

                // gather i,f,g,o within the quad (DPP, ~free)
                const float si = qb<0x00>(sv);
                const float sf = qb<0x55>(sv);
                const float sg = qb<0xAA>(sv);
                const float so = qb<0xFF>(sv);

                c = fmaf(sf, c, si * sg);
                const float e2 = fexp(2.f * c);
                const float th = fmaf(-2.f, frcp(1.f + e2), 1.f);   // tanh(c)
                h = so * th;

                if (writer) *op = h;
                op += HID;
            }
        } else {
            // ---- waves 1..7: precompute chunk ch+1 (overlaps recurrence) ----
            const int idx = tid - 64;
            const int nc  = ch + 1;
            if (nc < NCHUNK && idx < CHUNK)
                compute_row(nc * CHUNK + idx, &s_xg[nc & 1][idx * GATES], x,
                            Wmz1, bmz1, Wmz2, bmz2, Win1, bin1, Win2, bin2,
                            Wih, bih, bhh);
        }
    }
}

extern "C" void kernel_launch(void* const* d_in, const int* in_sizes, int n_in,
                              void* d_out, int out_size, void* d_ws, size_t ws_size,
                              hipStream_t stream)
{
    const float* x    = (const float*)d_in[0];
    const float* Wmz1 = (const float*)d_in[1];
    const float* bmz1 = (const float*)d_in[2];
    const float* Wmz2 = (const float*)d_in[3];
    const float* bmz2 = (const float*)d_in[4];
    const float* Win1 = (const float*)d_in[5];
    const float* bin1 = (const float*)d_in[6];
    const float* Win2 = (const float*)d_in[7];
    const float* bin2 = (const float*)d_in[8];
    const float* Wih  = (const float*)d_in[9];
    const float* Whh  = (const float*)d_in[10];
    const float* bih  = (const float*)d_in[11];
    const float* bhh  = (const float*)d_in[12];
    float* out = (float*)d_out;

    hipLaunchKernelGGL(msembed_kernel, dim3(1), dim3(512), 0, stream,
                       x, Wmz1, bmz1, Wmz2, bmz2, Win1, bin1, Win2, bin2,
                       Wih, Whh, bih, bhh, out);
}